// Round 5
// baseline (130.643 us; speedup 1.0000x reference)
//
#include <hip/hip_runtime.h>

#define SQ 2048
#define DM 512
#define NH 8
#define NSPLIT 4

typedef __bf16 bf16x8 __attribute__((ext_vector_type(8)));
typedef float f32x4 __attribute__((ext_vector_type(4)));
typedef unsigned short us8 __attribute__((ext_vector_type(8)));

__device__ __forceinline__ unsigned short f2bf(float f) {
    unsigned u = __builtin_bit_cast(unsigned, f);
    u += 0x7fffu + ((u >> 16) & 1u);     // round-to-nearest-even
    return (unsigned short)(u >> 16);
}
__device__ __forceinline__ unsigned short f2bf_trunc(float f) {
    return (unsigned short)(__builtin_bit_cast(unsigned, f) >> 16);
}

// ---------------------------------------------------------------------------
// Kernel 0: weight conversions only (X handled inline by qkv_mfma).
//  b [0,192):   Wq/Wk/Wv 64k x 64n tile transpose -> Wt[(p*8+h)][64 n][512 k]
//  b [192,256): Wo 64x64 tile transpose -> Wot [512 n][512 k] bf16
// ---------------------------------------------------------------------------
__global__ __launch_bounds__(256) void convert_w(
    const float* __restrict__ Wq, const float* __restrict__ Wk, const float* __restrict__ Wv,
    const float* __restrict__ Wo,
    unsigned short* __restrict__ Wt, unsigned short* __restrict__ Wot)
{
    const int b = blockIdx.x, tid = threadIdx.x;
    __shared__ float ld[64 * 68];
    float4* ld4 = reinterpret_cast<float4*>(ld);
    const int rr = tid >> 4, c4 = tid & 15;

    if (b < 192) {
        const int idx = b >> 3;              // p*8+h
        const int kt = b & 7;                // k-tile of 64
        const int p = idx >> 3, h = idx & 7;
        const float* src = ((p == 0) ? Wq : (p == 1) ? Wk : Wv)
                         + (size_t)h * 512 * 64 + (size_t)kt * 64 * 64;
        unsigned short* dst = Wt + (size_t)idx * 64 * 512 + kt * 64;
        #pragma unroll
        for (int it = 0; it < 4; it++) {
            int r = rr + 16 * it;            // k-row in tile
            ld4[r * 17 + c4] = reinterpret_cast<const float4*>(src + (size_t)r * 64)[c4];
        }
        __syncthreads();
        #pragma unroll
        for (int it = 0; it < 2; it++) {
            int slot = tid + it * 256;
            int n = slot >> 3, g = slot & 7;
            us8 o;
            #pragma unroll
            for (int i = 0; i < 8; i++)
                o[i] = f2bf(ld[(g * 8 + i) * 68 + n]);
            *reinterpret_cast<us8*>(dst + (size_t)n * 512 + g * 8) = o;
        }
    } else {
        const int ti = b - 192;              // 0..63
        const int kt = ti >> 3, nt = ti & 7;
        const float* src = Wo + (size_t)kt * 64 * 512 + nt * 64;
        #pragma unroll
        for (int it = 0; it < 4; it++) {
            int r = rr + 16 * it;
            ld4[r * 17 + c4] = reinterpret_cast<const float4*>(src + (size_t)r * 512)[c4];
        }
        __syncthreads();
        #pragma unroll
        for (int it = 0; it < 2; it++) {
            int slot = tid + it * 256;
            int n = slot >> 3, g = slot & 7;
            us8 o;
            #pragma unroll
            for (int i = 0; i < 8; i++)
                o[i] = f2bf(ld[(g * 8 + i) * 68 + n]);
            *reinterpret_cast<us8*>(Wot + (size_t)(nt * 64 + n) * 512 + kt * 64 + g * 8) = o;
        }
    }
}

// ---------------------------------------------------------------------------
// Kernel 1: QKV projections via bf16 MFMA, fp32 X converted during staging,
// double-buffered LDS, ONE barrier per K-chunk. grid (32, 8, 3), block 256.
// ---------------------------------------------------------------------------
__global__ __launch_bounds__(256) void qkv_mfma(
    const float* __restrict__ emb, const float* __restrict__ Kin, const float* __restrict__ Vin,
    const unsigned short* __restrict__ Wt,
    const float* __restrict__ bq, const float* __restrict__ bk, const float* __restrict__ bv,
    unsigned short* __restrict__ qo, unsigned short* __restrict__ ko, unsigned short* __restrict__ vo)
{
    const int p = blockIdx.z, h = blockIdx.y, s0 = blockIdx.x * 64;
    const float* X = (p == 0) ? emb : (p == 1) ? Kin : Vin;
    const unsigned short* W = Wt + (size_t)(p * 8 + h) * 64 * 512;
    const float* B = ((p == 0) ? bq : (p == 1) ? bk : bv) + h * 64;

    const int tid = threadIdx.x;
    const int w = tid >> 6, lane = tid & 63, cl = lane & 15, q4 = lane >> 4;
    const int sr = tid >> 3, sg = tid & 7;

    __shared__ unsigned short As[2][64 * 72];
    __shared__ unsigned short Bs[2][64 * 72];

    // stage chunk 0 (convert fp32 X -> bf16 inline)
    #pragma unroll
    for (int it = 0; it < 2; it++) {
        int r = sr + 32 * it;
        const float* xr = &X[(size_t)(s0 + r) * 512 + sg * 8];
        float4 f0 = *reinterpret_cast<const float4*>(xr);
        float4 f1 = *reinterpret_cast<const float4*>(xr + 4);
        us8 o;
        o[0] = f2bf(f0.x); o[1] = f2bf(f0.y); o[2] = f2bf(f0.z); o[3] = f2bf(f0.w);
        o[4] = f2bf(f1.x); o[5] = f2bf(f1.y); o[6] = f2bf(f1.z); o[7] = f2bf(f1.w);
        *reinterpret_cast<us8*>(&As[0][r * 72 + sg * 8]) = o;
        *reinterpret_cast<float4*>(&Bs[0][r * 72 + sg * 8]) =
            *reinterpret_cast<const float4*>(&W[(size_t)r * 512 + sg * 8]);
    }

    f32x4 acc[4] = {};

    for (int c = 0; c < 8; c++) {
        __syncthreads();
        const int buf = c & 1;
        const bool more = (c + 1 < 8);
        float4 x0[2], x1[2], br[2];
        if (more) {
            #pragma unroll
            for (int it = 0; it < 2; it++) {
                int r = sr + 32 * it;
                const float* xr = &X[(size_t)(s0 + r) * 512 + (c + 1) * 64 + sg * 8];
                x0[it] = *reinterpret_cast<const float4*>(xr);
                x1[it] = *reinterpret_cast<const float4*>(xr + 4);
                br[it] = *reinterpret_cast<const float4*>(
                    &W[(size_t)r * 512 + (c + 1) * 64 + sg * 8]);
            }
        }

        bf16x8 a0 = *reinterpret_cast<const bf16x8*>(&As[buf][(16 * w + cl) * 72 + q4 * 8]);
        bf16x8 a1 = *reinterpret_cast<const bf16x8*>(&As[buf][(16 * w + cl) * 72 + 32 + q4 * 8]);
        #pragma unroll
        for (int nn = 0; nn < 4; nn++) {
            bf16x8 b0 = *reinterpret_cast<const bf16x8*>(&Bs[buf][(16 * nn + cl) * 72 + q4 * 8]);
            bf16x8 b1 = *reinterpret_cast<const bf16x8*>(&Bs[buf][(16 * nn + cl) * 72 + 32 + q4 * 8]);
            acc[nn] = __builtin_amdgcn_mfma_f32_16x16x32_bf16(a0, b0, acc[nn], 0, 0, 0);
            acc[nn] = __builtin_amdgcn_mfma_f32_16x16x32_bf16(a1, b1, acc[nn], 0, 0, 0);
        }

        if (more) {
            const int nbuf = buf ^ 1;
            #pragma unroll
            for (int it = 0; it < 2; it++) {
                int r = sr + 32 * it;
                us8 o;
                o[0] = f2bf(x0[it].x); o[1] = f2bf(x0[it].y);
                o[2] = f2bf(x0[it].z); o[3] = f2bf(x0[it].w);
                o[4] = f2bf(x1[it].x); o[5] = f2bf(x1[it].y);
                o[6] = f2bf(x1[it].z); o[7] = f2bf(x1[it].w);
                *reinterpret_cast<us8*>(&As[nbuf][r * 72 + sg * 8]) = o;
                *reinterpret_cast<float4*>(&Bs[nbuf][r * 72 + sg * 8]) = br[it];
            }
        }
    }

    if (p == 0) {
        #pragma unroll
        for (int nn = 0; nn < 4; nn++) {
            int col = 16 * nn + cl;
            float bb = B[col];
            #pragma unroll
            for (int r = 0; r < 4; r++)
                qo[((size_t)h * SQ + s0 + 16 * w + q4 * 4 + r) * 64 + col] =
                    f2bf((acc[nn][r] + bb) * 0.125f);
        }
    } else if (p == 1) {
        #pragma unroll
        for (int nn = 0; nn < 4; nn++) {
            int col = 16 * nn + cl;
            float bb = B[col];
            #pragma unroll
            for (int r = 0; r < 4; r++)
                ko[((size_t)h * SQ + s0 + 16 * w + q4 * 4 + r) * 64 + col] =
                    f2bf(acc[nn][r] + bb);
        }
    } else {
        #pragma unroll
        for (int nn = 0; nn < 4; nn++) {
            int col = 16 * nn + cl;   // dv
            float bb = B[col];
            ushort4 o;
            o.x = f2bf(acc[nn][0] + bb);
            o.y = f2bf(acc[nn][1] + bb);
            o.z = f2bf(acc[nn][2] + bb);
            o.w = f2bf(acc[nn][3] + bb);
            *reinterpret_cast<ushort4*>(
                vo + ((size_t)h * 64 + col) * SQ + s0 + 16 * w + q4 * 4) = o;
        }
    }
}

// ---------------------------------------------------------------------------
// Kernel 2: flash attention, bf16 MFMA, no online max, KV-split x4.
// grid (32 = z*8+h, 32 = s-block): blocks sharing a KV quarter are id-congruent
// mod 8 -> same XCD (L2 locality heuristic). Emits unnormalized partial O
// (fp32) + partial row-sum l.
// ---------------------------------------------------------------------------
#define PW 72

__global__ __launch_bounds__(256) void attn_fwd(
    const unsigned short* __restrict__ qbf,   // [h][2048][64], *0.125 folded
    const unsigned short* __restrict__ kbf,   // [h][2048][64]
    const unsigned short* __restrict__ vbf,   // [h][64][2048] transposed
    float* __restrict__ Opart,                // [z*8+h][2048][64]
    float* __restrict__ lpart)                // [z*8+h][2048]
{
    const int bx = blockIdx.x;                // z*8+h
    const int z = bx >> 3, h = bx & 7;
    const int s0 = blockIdx.y * 64;
    const int tid = threadIdx.x;
    const int w = tid >> 6, lane = tid & 63, cl = lane & 15, q4 = lane >> 4;
    const int NT = SQ / 64 / NSPLIT;          // 8 tiles per block
    const int t0 = z * NT;

    __shared__ unsigned short Ks[2][64 * PW];
    __shared__ unsigned short Vs[2][64 * PW];
    __shared__ unsigned short Ps[4][16 * PW];

    bf16x8 aq0 = *reinterpret_cast<const bf16x8*>(
        &qbf[((size_t)h * SQ + s0 + 16 * w + cl) * 64 + q4 * 8]);
    bf16x8 aq1 = *reinterpret_cast<const bf16x8*>(
        &qbf[((size_t)h * SQ + s0 + 16 * w + cl) * 64 + 32 + q4 * 8]);

    const int sr = tid >> 3, sg = tid & 7;

    #pragma unroll
    for (int it = 0; it < 2; it++) {
        int r = sr + 32 * it;
        *reinterpret_cast<float4*>(&Ks[0][r * PW + sg * 8]) =
            *reinterpret_cast<const float4*>(&kbf[((size_t)h * SQ + t0 * 64 + r) * 64 + sg * 8]);
        *reinterpret_cast<float4*>(&Vs[0][r * PW + sg * 8]) =
            *reinterpret_cast<const float4*>(&vbf[((size_t)h * 64 + r) * SQ + t0 * 64 + sg * 8]);
    }

    f32x4 o_acc[4] = {};
    float lsum[4] = {};

    for (int tl = 0; tl < NT; tl++) {
        __syncthreads();
        const int buf = tl & 1;
        const bool more = (tl + 1 < NT);
        float4 kr[2], vr[2];
        if (more) {
            #pragma unroll
            for (int it = 0; it < 2; it++) {
                int r = sr + 32 * it;
                kr[it] = *reinterpret_cast<const float4*>(
                    &kbf[((size_t)h * SQ + (t0 + tl + 1) * 64 + r) * 64 + sg * 8]);
                vr[it] = *reinterpret_cast<const float4*>(
                    &vbf[((size_t)h * 64 + r) * SQ + (t0 + tl + 1) * 64 + sg * 8]);
            }
        }

        // ---- S = Q K^T ----
        f32x4 s_acc[4] = {};
        #pragma unroll
        for (int nn = 0; nn < 4; nn++) {
            bf16x8 b0 = *reinterpret_cast<const bf16x8*>(&Ks[buf][(16 * nn + cl) * PW + q4 * 8]);
            bf16x8 b1 = *reinterpret_cast<const bf16x8*>(&Ks[buf][(16 * nn + cl) * PW + 32 + q4 * 8]);
            s_acc[nn] = __builtin_amdgcn_mfma_f32_16x16x32_bf16(aq0, b0, s_acc[nn], 0, 0, 0);
            s_acc[nn] = __builtin_amdgcn_mfma_f32_16x16x32_bf16(aq1, b1, s_acc[nn], 0, 0, 0);
        }

        // ---- p = exp(s), partial row sums, repack for A-operand ----
        // truncation-convert: bias cancels between P·V numerator and l denom
        #pragma unroll
        for (int r = 0; r < 4; r++) {
            #pragma unroll
            for (int nn = 0; nn < 4; nn++) {
                float pv = __expf(s_acc[nn][r]);
                lsum[r] += pv;
                Ps[w][(q4 * 4 + r) * PW + 16 * nn + cl] = f2bf_trunc(pv);
            }
        }
        bf16x8 ap0 = *reinterpret_cast<const bf16x8*>(&Ps[w][cl * PW + q4 * 8]);
        bf16x8 ap1 = *reinterpret_cast<const bf16x8*>(&Ps[w][cl * PW + 32 + q4 * 8]);

        // ---- O += P V ----
        #pragma unroll
        for (int nn = 0; nn < 4; nn++) {
            bf16x8 b0 = *reinterpret_cast<const bf16x8*>(&Vs[buf][(16 * nn + cl) * PW + q4 * 8]);
            bf16x8 b1 = *reinterpret_cast<const bf16x8*>(&Vs[buf][(16 * nn + cl) * PW + 32 + q4 * 8]);
            o_acc[nn] = __builtin_amdgcn_mfma_f32_16x16x32_bf16(ap0, b0, o_acc[nn], 0, 0, 0);
            o_acc[nn] = __builtin_amdgcn_mfma_f32_16x16x32_bf16(ap1, b1, o_acc[nn], 0, 0, 0);
        }

        if (more) {
            const int nbuf = buf ^ 1;
            #pragma unroll
            for (int it = 0; it < 2; it++) {
                int r = sr + 32 * it;
                *reinterpret_cast<float4*>(&Ks[nbuf][r * PW + sg * 8]) = kr[it];
                *reinterpret_cast<float4*>(&Vs[nbuf][r * PW + sg * 8]) = vr[it];
            }
        }
    }

    #pragma unroll
    for (int r = 0; r < 4; r++) {
        float v = lsum[r];
        #pragma unroll
        for (int off = 1; off < 16; off <<= 1) v += __shfl_xor(v, off);
        lsum[r] = v;
    }

    const size_t zb = (size_t)bx;
    if (cl == 0) {
        #pragma unroll
        for (int r = 0; r < 4; r++)
            lpart[zb * SQ + s0 + 16 * w + q4 * 4 + r] = lsum[r];
    }
    #pragma unroll
    for (int nn = 0; nn < 4; nn++)
        #pragma unroll
        for (int r = 0; r < 4; r++)
            Opart[(zb * SQ + s0 + 16 * w + q4 * 4 + r) * 64 + 16 * nn + cl] = o_acc[nn][r];
}

// ---------------------------------------------------------------------------
// Kernel 3: output projection with FUSED split-combine: A-tile staged by
// summing 4 z-partials + normalizing by 1/sum(l) inline (invL in LDS), then
// plain bf16 MFMA against Wot. grid (32 s, 8 n), block 256.
// ---------------------------------------------------------------------------
__global__ __launch_bounds__(256) void out_proj(
    const float* __restrict__ Opart, const float* __restrict__ lpart,
    const unsigned short* __restrict__ Wot,
    const float* __restrict__ bo, float* __restrict__ out)
{
    const int s0 = blockIdx.x * 64, n0 = blockIdx.y * 64;
    const int tid = threadIdx.x;
    const int w = tid >> 6, lane = tid & 63, cl = lane & 15, q4 = lane >> 4;
    const int sr = tid >> 3, sg = tid & 7;

    __shared__ unsigned short As[2][64 * 72];
    __shared__ unsigned short Bs[2][64 * 72];
    __shared__ float invL[512];   // [h][s_local]

    // 1/sum_z l for each (head, local row)
    #pragma unroll
    for (int k = 0; k < 2; k++) {
        int idx = tid * 2 + k;                    // h*64 + s_local
        int hh = idx >> 6, ss = idx & 63;
        float l = 0.f;
        #pragma unroll
        for (int z = 0; z < NSPLIT; z++)
            l += lpart[(size_t)(z * 8 + hh) * SQ + s0 + ss];
        invL[idx] = 1.0f / l;
    }
    __syncthreads();

    // stage chunk 0 (= head 0)
    #pragma unroll
    for (int it = 0; it < 2; it++) {
        int r = sr + 32 * it;
        float o[8] = {};
        #pragma unroll
        for (int z = 0; z < NSPLIT; z++) {
            const float4* pp = reinterpret_cast<const float4*>(
                &Opart[((size_t)(z * 8) * SQ + s0 + r) * 64 + sg * 8]);
            float4 a = pp[0], b = pp[1];
            o[0] += a.x; o[1] += a.y; o[2] += a.z; o[3] += a.w;
            o[4] += b.x; o[5] += b.y; o[6] += b.z; o[7] += b.w;
        }
        float il = invL[r];
        us8 pk;
        #pragma unroll
        for (int i = 0; i < 8; i++) pk[i] = f2bf(o[i] * il);
        *reinterpret_cast<us8*>(&As[0][r * 72 + sg * 8]) = pk;
        *reinterpret_cast<float4*>(&Bs[0][r * 72 + sg * 8]) =
            *reinterpret_cast<const float4*>(&Wot[(size_t)(n0 + r) * 512 + sg * 8]);
    }

    f32x4 acc[4] = {};

    for (int c = 0; c < 8; c++) {
        __syncthreads();
        const int buf = c & 1;
        const bool more = (c + 1 < 8);
        float4 pre[2][NSPLIT][2];
        float4 wr[2];
        if (more) {
            const int hn = c + 1;
            #pragma unroll
            for (int it = 0; it < 2; it++) {
                int r = sr + 32 * it;
                #pragma unroll
                for (int z = 0; z < NSPLIT; z++) {
                    const float4* pp = reinterpret_cast<const float4*>(
                        &Opart[((size_t)(z * 8 + hn) * SQ + s0 + r) * 64 + sg * 8]);
                    pre[it][z][0] = pp[0];
                    pre[it][z][1] = pp[1];
                }
                wr[it] = *reinterpret_cast<const float4*>(
                    &Wot[(size_t)(n0 + r) * 512 + hn * 64 + sg * 8]);
            }
        }

        bf16x8 a0 = *reinterpret_cast<const bf16x8*>(&As[buf][(16 * w + cl) * 72 + q4 * 8]);
        bf16x8 a1 = *reinterpret_cast<const bf16x8*>(&As[buf][(16 * w + cl) * 72 + 32 + q4 * 8]);
        #pragma unroll
        for (int nn = 0; nn < 4; nn++) {
            bf16x8 b0 = *reinterpret_cast<const bf16x8*>(&Bs[buf][(16 * nn + cl) * 72 + q4 * 8]);
            bf16x8 b1 = *reinterpret_cast<const bf16x8*>(&Bs[buf][(16 * nn + cl) * 72 + 32 + q4 * 8]);
            acc[nn] = __builtin_amdgcn_mfma_f32_16x16x32_bf16(a0, b0, acc[nn], 0, 0, 0);
            acc[nn] = __builtin_amdgcn_mfma_f32_16x16x32_bf16(a1, b1, acc[nn], 0, 0, 0);
        }

        if (more) {
            const int nbuf = buf ^ 1;
            const int hn = c + 1;
            #pragma unroll
            for (int it = 0; it < 2; it++) {
                int r = sr + 32 * it;
                float o[8] = {};
                #pragma unroll
                for (int z = 0; z < NSPLIT; z++) {
                    float4 a = pre[it][z][0], b = pre[it][z][1];
                    o[0] += a.x; o[1] += a.y; o[2] += a.z; o[3] += a.w;
                    o[4] += b.x; o[5] += b.y; o[6] += b.z; o[7] += b.w;
                }
                float il = invL[hn * 64 + r];
                us8 pk;
                #pragma unroll
                for (int i = 0; i < 8; i++) pk[i] = f2bf(o[i] * il);
                *reinterpret_cast<us8*>(&As[nbuf][r * 72 + sg * 8]) = pk;
                *reinterpret_cast<float4*>(&Bs[nbuf][r * 72 + sg * 8]) = wr[it];
            }
        }
    }

    #pragma unroll
    for (int nn = 0; nn < 4; nn++) {
        int col = n0 + 16 * nn + cl;
        float bb = bo[col];
        #pragma unroll
        for (int r = 0; r < 4; r++)
            out[(size_t)(s0 + 16 * w + q4 * 4 + r) * DM + col] = acc[nn][r] + bb;
    }
}

extern "C" void kernel_launch(void* const* d_in, const int* in_sizes, int n_in,
                              void* d_out, int out_size, void* d_ws, size_t ws_size,
                              hipStream_t stream) {
    const float* emb = (const float*)d_in[0];
    const float* Kin = (const float*)d_in[1];
    const float* Vin = (const float*)d_in[2];
    const float* Wq  = (const float*)d_in[3];
    const float* bq  = (const float*)d_in[4];
    const float* Wk  = (const float*)d_in[5];
    const float* bk  = (const float*)d_in[6];
    const float* Wv  = (const float*)d_in[7];
    const float* bv  = (const float*)d_in[8];
    const float* Wo  = (const float*)d_in[9];
    const float* bo  = (const float*)d_in[10];
    float* out = (float*)d_out;

    unsigned short* p = (unsigned short*)d_ws;
    unsigned short* Wt  = p; p += (size_t)24 * 64 * 512;     // 1.5 MB
    unsigned short* Wot = p; p += (size_t)512 * 512;         // 0.5 MB
    unsigned short* qbf = p; p += (size_t)NH * SQ * 64;      // 2 MB
    unsigned short* kbf = p; p += (size_t)NH * SQ * 64;
    unsigned short* vbf = p; p += (size_t)NH * SQ * 64;
    float* Opart = (float*)p;                                // 16 MB
    float* lpart = Opart + (size_t)NSPLIT * NH * SQ * 64;    // 256 KB

    convert_w<<<256, 256, 0, stream>>>(Wq, Wk, Wv, Wo, Wt, Wot);
    qkv_mfma<<<dim3(32, 8, 3), 256, 0, stream>>>(emb, Kin, Vin, Wt, bq, bk, bv,
                                                 qbf, kbf, vbf);
    attn_fwd<<<dim3(32, 32), 256, 0, stream>>>(qbf, kbf, vbf, Opart, lpart);
    out_proj<<<dim3(32, 8), 256, 0, stream>>>(Opart, lpart, Wot, bo, out);
}